// Round 4
// baseline (720.305 us; speedup 1.0000x reference)
//
#include <hip/hip_runtime.h>
#include <stdint.h>

#define B_ 4
#define C_ 512
#define CQ_ 64
#define H_ 128
#define W_ 128
#define HW_ 16384

typedef unsigned short u16;
typedef unsigned int u32;
typedef __attribute__((ext_vector_type(8))) __bf16 bf16x8;
typedef __attribute__((ext_vector_type(4))) float f32x4;

__device__ __forceinline__ u16 f2bf(float f) {
    u32 v; __builtin_memcpy(&v, &f, 4);
    v = (v + 0x7FFFu + ((v >> 16) & 1u)) >> 16;
    return (u16)v;
}
__device__ __forceinline__ float bf2f(u16 a) {
    u32 v = ((u32)a) << 16; float f; __builtin_memcpy(&f, &v, 4); return f;
}

// ---- workspace map (u16 elements), total 117,440,512 elems = 234,881,024 B ----
// XT (x^T bf16, [b][p][c]) dies after proj; CV reuses its space (vattn runs later).
// WB (W bf16) dies after proj; QT region (written by transpose_qk, post-proj) reuses it.
// WS_VT holds VV[b][w][cc][h2]: the vertical-attention V operand pre-arranged so
// each vattn MFMA A-fragment (8 consecutive h2 at fixed cc) is one contiguous 16B load.
#define WS_XT  0u
#define WS_CV  0u
#define WS_Q   33554432u
#define WS_K   37748736u
#define WS_V   41943040u   // layout [b][h][c][w]
#define WS_QT  75497472u
#define WS_KT  79691776u
#define WS_WB  75497472u   // aliases QT
#define WS_VT  83886080u   // layout [b][w][cc][h2], cc=(c&3)*128+h, h2=c>>2

// ---------------------------------------------------------------------------
// prep_x: x f32 [b][c][p] -> XT bf16 [b][p][c]   (convert once + transpose)
// ---------------------------------------------------------------------------
__global__ __launch_bounds__(256) void prep_x(const float* __restrict__ x, u16* __restrict__ ws)
{
    __shared__ __align__(16) u16 tl[64][72];
    const int t = threadIdx.x;
    const int pt = blockIdx.x, ct = blockIdx.y, b = blockIdx.z;
    const int p0 = pt * 64, c0 = ct * 64;
    const float* xb = x + ((u32)(b*C_ + c0))*HW_ + p0;
    #pragma unroll
    for (int pass = 0; pass < 4; ++pass) {
        int ci = pass*256 + t, cl = ci >> 4, p4 = ci & 15;
        float4 d = *reinterpret_cast<const float4*>(xb + (u32)cl*HW_ + p4*4);
        tl[p4*4+0][cl] = f2bf(d.x); tl[p4*4+1][cl] = f2bf(d.y);
        tl[p4*4+2][cl] = f2bf(d.z); tl[p4*4+3][cl] = f2bf(d.w);
    }
    __syncthreads();
    u16* dst = ws + WS_XT + ((u32)((b<<14) + p0))*512 + c0;
    #pragma unroll
    for (int pass = 0; pass < 2; ++pass) {
        int ci = pass*256 + t, pr = ci >> 3, k8 = ci & 7;
        uint4 d = *reinterpret_cast<const uint4*>(&tl[pr][k8*8]);
        *reinterpret_cast<uint4*>(dst + (u32)pr*512 + k8*8) = d;
    }
}

// ---------------------------------------------------------------------------
// prep_w: concat [Wq;Wk;Wv] f32 -> WB bf16 [640][512]. grid 320, 256 thr.
// ---------------------------------------------------------------------------
__global__ __launch_bounds__(256) void prep_w(const float* __restrict__ Wq, const float* __restrict__ Wk,
                                              const float* __restrict__ Wv, u16* __restrict__ ws)
{
    const int f = (blockIdx.x*256 + threadIdx.x)*4;
    const float* src;
    if (f < 32768)      src = Wq + f;
    else if (f < 65536) src = Wk + (f - 32768);
    else                src = Wv + (f - 65536);
    float4 d = *reinterpret_cast<const float4*>(src);
    u16 e[4] = { f2bf(d.x), f2bf(d.y), f2bf(d.z), f2bf(d.w) };
    *reinterpret_cast<uint2*>(ws + WS_WB + f) = *reinterpret_cast<const uint2*>(e);
}

// ---------------------------------------------------------------------------
// proj: D[o][p] = sum_c WB[o][c]*xT[p][c] (+bias). 128x128 tile, BK=64.
// Flat grid 2560, CHUNKED XCD swizzle (fix of R3's strided variant): work is
// ordered panel-major f = p*5+bm; XCD x owns the contiguous chunk
// f in [320x, 320x+320) = 64 consecutive panels. bid = (f%320)*8 + x.
//  - same-panel 5 m-tiles adjacent in time on one XCD -> XT panel fetched
//    from HBM once (R3 confirmed: FETCH 177->69 MB)
//  - per-XCD writes cover a dense contiguous range -> L2 lines complete
//    before eviction (fixes R3's 477 MB write explosion from 2KB-strided
//    panels hitting ~6% of L2 sets)
// K-staging register-prefetched. q,k -> [b][cq][hw]; v -> [b][h][c][w].
// ---------------------------------------------------------------------------
__global__ __launch_bounds__(256) void proj_kernel(const float* __restrict__ bq, const float* __restrict__ bk,
                                                   const float* __restrict__ bv, u16* __restrict__ ws)
{
    __shared__ __align__(16) u16 As[128][72];
    __shared__ __align__(16) u16 Bs[128][72];
    const int t = threadIdx.x;
    const int bid = blockIdx.x;
    const int x8 = bid & 7, j = bid >> 3;        // j in [0,320)
    const int f = x8*320 + j;                    // f in [0,2560)
    const int p = f / 5, bm = f - 5*p;           // p: panel id in [0,512), bm in [0,5)
    const int b = p >> 7, bn = p & 127;
    const int m0 = bm*128, p0 = bn*128;
    const u16* WB = ws + WS_WB;
    const u16* XT = ws + WS_XT + ((u32)((b<<14) + p0))*512;
    const int wv = t >> 6, ln = t & 63, quad = ln >> 4, col = ln & 15;
    const int mh = (wv>>1)*64, nh = (wv&1)*64;
    const int srow = t >> 3, sk8 = t & 7;        // staging row/col (pass adds 32 rows)

    f32x4 acc[4][4];
    #pragma unroll
    for (int mt = 0; mt < 4; ++mt)
        #pragma unroll
        for (int nt = 0; nt < 4; ++nt) acc[mt][nt] = (f32x4){0.f,0.f,0.f,0.f};

    uint4 ra[4], rb[4];
    #pragma unroll
    for (int pass = 0; pass < 4; ++pass) {
        int row = pass*32 + srow;
        ra[pass] = *reinterpret_cast<const uint4*>(WB + (u32)(m0+row)*512 + sk8*8);
        rb[pass] = *reinterpret_cast<const uint4*>(XT + (u32)row*512 + sk8*8);
    }

    for (int c0 = 0; c0 < 512; c0 += 64) {
        #pragma unroll
        for (int pass = 0; pass < 4; ++pass) {
            int row = pass*32 + srow;
            *reinterpret_cast<uint4*>(&As[row][sk8*8]) = ra[pass];
            *reinterpret_cast<uint4*>(&Bs[row][sk8*8]) = rb[pass];
        }
        __syncthreads();
        if (c0 + 64 < 512) {
            #pragma unroll
            for (int pass = 0; pass < 4; ++pass) {
                int row = pass*32 + srow;
                ra[pass] = *reinterpret_cast<const uint4*>(WB + (u32)(m0+row)*512 + c0 + 64 + sk8*8);
                rb[pass] = *reinterpret_cast<const uint4*>(XT + (u32)row*512 + c0 + 64 + sk8*8);
            }
        }
        #pragma unroll
        for (int ks = 0; ks < 2; ++ks) {
            const int kk = ks*32 + quad*8;
            bf16x8 am[4], bn_[4];
            #pragma unroll
            for (int mt = 0; mt < 4; ++mt) am[mt]  = *reinterpret_cast<const bf16x8*>(&As[mh + mt*16 + col][kk]);
            #pragma unroll
            for (int nt = 0; nt < 4; ++nt) bn_[nt] = *reinterpret_cast<const bf16x8*>(&Bs[nh + nt*16 + col][kk]);
            #pragma unroll
            for (int mt = 0; mt < 4; ++mt)
                #pragma unroll
                for (int nt = 0; nt < 4; ++nt)
                    acc[mt][nt] = __builtin_amdgcn_mfma_f32_16x16x32_bf16(am[mt], bn_[nt], acc[mt][nt], 0, 0, 0);
        }
        __syncthreads();
    }
    const int h = bn;
    #pragma unroll
    for (int mt = 0; mt < 4; ++mt) {
        const int obase = m0 + mh + mt*16 + quad*4;
        #pragma unroll
        for (int r = 0; r < 4; ++r) {
            const int o = obase + r;
            float bb; u16* dst;
            if (o < 64)       { bb = bq[o];     dst = ws + WS_Q + ((u32)((b<<6) + o))*HW_ + p0; }
            else if (o < 128) { bb = bk[o-64];  dst = ws + WS_K + ((u32)((b<<6) + (o-64)))*HW_ + p0; }
            else              { bb = bv[o-128]; dst = ws + WS_V + (u32)b*8388608u + (u32)h*65536u + (u32)(o-128)*128u; }
            #pragma unroll
            for (int nt = 0; nt < 4; ++nt) {
                int pl = nh + nt*16 + col;
                dst[pl] = f2bf(acc[mt][nt][r] + bb);
            }
        }
    }
}

// ---------------------------------------------------------------------------
// transpose_qk: 512 images (q then k, contiguous) [h][w] -> [w][h]
// Vectorized: uint4 global loads (8 u16/lane), LDS scatter-transpose,
// uint2 (4 u16) global stores. LDS stride 70 u16 (35 dwords, odd) ->
// phase-1 writes 4-way, phase-2 u32 reads 2-way (free).
// ---------------------------------------------------------------------------
__global__ __launch_bounds__(256) void transpose_qk(u16* __restrict__ ws)
{
    __shared__ u16 tl[64][70];   // [w][h]
    const int t = threadIdx.x;
    const int tile = blockIdx.x, img = blockIdx.y;
    const int h0 = (tile >> 1) * 64, w0 = (tile & 1) * 64;
    const u16* src = ws + WS_Q + (u32)img * HW_;
    u16* dst = ws + WS_QT + (u32)img * HW_;
    #pragma unroll
    for (int pass = 0; pass < 2; ++pass) {
        int ci = pass*256 + t, hl = ci >> 3, w8 = ci & 7;
        uint4 d = *reinterpret_cast<const uint4*>(src + (u32)(h0+hl)*W_ + w0 + w8*8);
        const u16* e = reinterpret_cast<const u16*>(&d);
        #pragma unroll
        for (int j = 0; j < 8; ++j) tl[w8*8+j][hl] = e[j];
    }
    __syncthreads();
    #pragma unroll
    for (int pass = 0; pass < 4; ++pass) {
        int ci = pass*256 + t, wl = ci >> 4, h4 = ci & 15;
        uint2 d;
        d.x = *reinterpret_cast<const u32*>(&tl[wl][h4*4]);
        d.y = *reinterpret_cast<const u32*>(&tl[wl][h4*4+2]);
        *reinterpret_cast<uint2*>(dst + (u32)(w0+wl)*H_ + h0 + h4*4) = d;
    }
}

// ---------------------------------------------------------------------------
// shuffle_v: V [b][h][c][w] -> VV [b][w][cc][h2], cc=(c&3)*128+h, h2=c>>2.
// Stored so vattn's MFMA A-fragments (8 consecutive h2, fixed cc) are single
// contiguous 16B global loads (mirrors hattn's direct-from-global V access).
// ---------------------------------------------------------------------------
__global__ __launch_bounds__(256) void shuffle_v(u16* __restrict__ ws)
{
    __shared__ u16 tl[128][134];   // [c_local][w], stride 134 u16 = 67 dw (odd)
    const int t = threadIdx.x;
    const int ct = blockIdx.x, h = blockIdx.y, b = blockIdx.z;
    const int c0 = ct * 128;
    const u16* src = ws + WS_V + (u32)b*8388608u + (u32)h*65536u + (u32)c0*128u;
    #pragma unroll
    for (int pass = 0; pass < 8; ++pass) {
        int ci = pass*256 + t, cl = ci >> 4, w8 = ci & 15;
        uint4 d = *reinterpret_cast<const uint4*>(src + (u32)cl*128u + w8*8);
        *reinterpret_cast<uint4*>(&tl[cl][w8*8]) = d;
    }
    __syncthreads();
    u16* dst = ws + WS_VT + (u32)b*8388608u;
    #pragma unroll
    for (int pass = 0; pass < 8; ++pass) {
        int ci = pass*256 + t;               // [0,2048)
        int w = ci >> 4, g = (ci >> 2) & 3, q4 = ci & 3;
        u16 e[8];
        #pragma unroll
        for (int jj = 0; jj < 8; ++jj)
            e[jj] = tl[4*(q4*8 + jj) + g][w];
        *reinterpret_cast<uint4*>(dst + (u32)w*65536u + (u32)(g*128 + h)*128u + (c0>>2) + q4*8)
            = *reinterpret_cast<const uint4*>(e);
    }
}

// shared LDS for hattn: q/k staging overlapped with softmaxed A
union __align__(16) ShAttn {
    struct QK { u16 q[128][72]; u16 kt[128][72]; } qk;  // 36864 B
    u16 a[128][136];                                    // 34816 B
};

// ---------------------------------------------------------------------------
// hattn: one block per (b,h). S[w1][w2]=sum_i q[w1][i]*kh[i][w2],
// kh[i][w2] = k[w2&63][2i+(w2>>6)].  ch[cc][w1]=sum_w2 A[w1][w2]*v[cc][w2].
// V in [b][h][c][w] -> A-operand fragments are 16B global loads within 4 KB.
// Writes raw ch (f32) -> d_out.
// ---------------------------------------------------------------------------
__global__ __launch_bounds__(256) void hattn_kernel(const u16* __restrict__ ws, float* __restrict__ outp)
{
    __shared__ ShAttn sh;
    const int t = threadIdx.x;
    const int h = blockIdx.x, b = blockIdx.y;
    const u16* qsrc = ws + WS_Q + (u32)(b*CQ_)*HW_ + h*W_;
    const u16* ksrc = ws + WS_K + (u32)(b*CQ_)*HW_ + h*W_;

    for (int e = t; e < 8192; e += 256) {
        int cq = e >> 7, w = e & 127;
        sh.qk.q[w][cq] = qsrc[cq*HW_ + w];
        u16 kv = ksrc[cq*HW_ + w];
        sh.qk.kt[cq + ((w & 1) << 6)][w >> 1] = kv;   // kt[w2][i] = kh[i][w2]
    }
    __syncthreads();

    const int wv = t >> 6, ln = t & 63, quad = ln >> 4, col = ln & 15;
    f32x4 accs[2][8];
    #pragma unroll
    for (int mt = 0; mt < 2; ++mt)
        #pragma unroll
        for (int nt = 0; nt < 8; ++nt) accs[mt][nt] = (f32x4){0.f,0.f,0.f,0.f};

    #pragma unroll
    for (int ks = 0; ks < 2; ++ks) {
        bf16x8 bfv[8];
        #pragma unroll
        for (int nt = 0; nt < 8; ++nt)
            bfv[nt] = *reinterpret_cast<const bf16x8*>(&sh.qk.kt[nt*16 + col][ks*32 + quad*8]);
        #pragma unroll
        for (int mt = 0; mt < 2; ++mt) {
            bf16x8 af = *reinterpret_cast<const bf16x8*>(&sh.qk.q[(wv*2 + mt)*16 + col][ks*32 + quad*8]);
            #pragma unroll
            for (int nt = 0; nt < 8; ++nt)
                accs[mt][nt] = __builtin_amdgcn_mfma_f32_16x16x32_bf16(af, bfv[nt], accs[mt][nt], 0, 0, 0);
        }
    }
    #pragma unroll
    for (int mt = 0; mt < 2; ++mt) {
        #pragma unroll
        for (int r = 0; r < 4; ++r) {
            float mx = accs[mt][0][r];
            #pragma unroll
            for (int nt = 1; nt < 8; ++nt) mx = fmaxf(mx, accs[mt][nt][r]);
            #pragma unroll
            for (int d = 1; d <= 8; d <<= 1) mx = fmaxf(mx, __shfl_xor(mx, d, 64));
            float sum = 0.f;
            #pragma unroll
            for (int nt = 0; nt < 8; ++nt) { float ev = __expf(accs[mt][nt][r] - mx); accs[mt][nt][r] = ev; sum += ev; }
            #pragma unroll
            for (int d = 1; d <= 8; d <<= 1) sum += __shfl_xor(sum, d, 64);
            float inv = 1.f / sum;
            #pragma unroll
            for (int nt = 0; nt < 8; ++nt) accs[mt][nt][r] *= inv;
        }
    }
    __syncthreads();
    #pragma unroll
    for (int mt = 0; mt < 2; ++mt)
        #pragma unroll
        for (int nt = 0; nt < 8; ++nt)
            #pragma unroll
            for (int r = 0; r < 4; ++r) {
                int w1 = (wv*2 + mt)*16 + quad*4 + r;
                int w2 = nt*16 + col;
                sh.a[w1][w2] = f2bf(accs[mt][nt][r]);
            }
    __syncthreads();

    const u16* vsrc = ws + WS_V + (u32)b*8388608u + (u32)h*65536u;   // [c][w], rows 128
    float* chout = outp + (u32)(b*C_)*HW_ + h*W_;
    const int ccw = wv * 128;
    for (int mp = 0; mp < 4; ++mp) {
        f32x4 accv[2][8];
        #pragma unroll
        for (int mi = 0; mi < 2; ++mi)
            #pragma unroll
            for (int nt = 0; nt < 8; ++nt) accv[mi][nt] = (f32x4){0.f,0.f,0.f,0.f};
        #pragma unroll
        for (int ks = 0; ks < 4; ++ks) {
            bf16x8 bfv[8];
            #pragma unroll
            for (int nt = 0; nt < 8; ++nt)
                bfv[nt] = *reinterpret_cast<const bf16x8*>(&sh.a[nt*16 + col][ks*32 + quad*8]);
            #pragma unroll
            for (int mi = 0; mi < 2; ++mi) {
                int cct = ccw + (mp*2 + mi)*16;
                bf16x8 af = *reinterpret_cast<const bf16x8*>(&vsrc[(u32)(cct + col)*128u + ks*32 + quad*8]);
                #pragma unroll
                for (int nt = 0; nt < 8; ++nt)
                    accv[mi][nt] = __builtin_amdgcn_mfma_f32_16x16x32_bf16(af, bfv[nt], accv[mi][nt], 0, 0, 0);
            }
        }
        #pragma unroll
        for (int mi = 0; mi < 2; ++mi)
            #pragma unroll
            for (int nt = 0; nt < 8; ++nt)
                #pragma unroll
                for (int r = 0; r < 4; ++r) {
                    int cc = ccw + (mp*2 + mi)*16 + quad*4 + r;
                    int w1 = nt*16 + col;
                    chout[(u32)cc*HW_ + w1] = accv[mi][nt][r];
                }
    }
}

// LDS for vattn: qk staging / softmaxed A (V read direct from global VV)
union __align__(16) ShV {
    struct QK { u16 q[128][72]; u16 kt[128][72]; } qk;  // 36864 B
    u16 a[128][136];                                    // 34816 B
};

// ---------------------------------------------------------------------------
// vattn: one block per (b,w). qv[h1][i]=qT[h1>>1][w][64*(h1&1)+i];
// kv[i][h2]=kT[i][w][h2]; vv[h2][cc]=VV[b][w][cc][h2] (pre-arranged by
// shuffle_v) -> A-operand fragments are contiguous 16B global loads; no V
// staging, no per-chunk barriers.
// Writes cv^T [b][cc][w][h1] bf16 -> WS_CV.
// ---------------------------------------------------------------------------
__global__ __launch_bounds__(256) void vattn_kernel(u16* __restrict__ ws)
{
    __shared__ ShV sh;
    const int t = threadIdx.x;
    const int w = blockIdx.x, b = blockIdx.y;
    const u16* qTs = ws + WS_QT + (u32)(b*CQ_)*HW_ + w*H_;
    const u16* kTs = ws + WS_KT + (u32)(b*CQ_)*HW_ + w*H_;

    for (int e = t; e < 8192; e += 256) {
        int cq = e >> 7, hh = e & 127;
        sh.qk.q[2*cq + (hh >> 6)][hh & 63] = qTs[cq*HW_ + hh];
        sh.qk.kt[hh][cq] = kTs[cq*HW_ + hh];
    }
    __syncthreads();

    const int wv = t >> 6, ln = t & 63, quad = ln >> 4, col = ln & 15;
    f32x4 accs[2][8];
    #pragma unroll
    for (int mt = 0; mt < 2; ++mt)
        #pragma unroll
        for (int nt = 0; nt < 8; ++nt) accs[mt][nt] = (f32x4){0.f,0.f,0.f,0.f};

    #pragma unroll
    for (int ks = 0; ks < 2; ++ks) {
        bf16x8 bfv[8];
        #pragma unroll
        for (int nt = 0; nt < 8; ++nt)
            bfv[nt] = *reinterpret_cast<const bf16x8*>(&sh.qk.kt[nt*16 + col][ks*32 + quad*8]);
        #pragma unroll
        for (int mt = 0; mt < 2; ++mt) {
            bf16x8 af = *reinterpret_cast<const bf16x8*>(&sh.qk.q[(wv*2 + mt)*16 + col][ks*32 + quad*8]);
            #pragma unroll
            for (int nt = 0; nt < 8; ++nt)
                accs[mt][nt] = __builtin_amdgcn_mfma_f32_16x16x32_bf16(af, bfv[nt], accs[mt][nt], 0, 0, 0);
        }
    }
    #pragma unroll
    for (int mt = 0; mt < 2; ++mt) {
        #pragma unroll
        for (int r = 0; r < 4; ++r) {
            float mx = accs[mt][0][r];
            #pragma unroll
            for (int nt = 1; nt < 8; ++nt) mx = fmaxf(mx, accs[mt][nt][r]);
            #pragma unroll
            for (int d = 1; d <= 8; d <<= 1) mx = fmaxf(mx, __shfl_xor(mx, d, 64));
            float sum = 0.f;
            #pragma unroll
            for (int nt = 0; nt < 8; ++nt) { float ev = __expf(accs[mt][nt][r] - mx); accs[mt][nt][r] = ev; sum += ev; }
            #pragma unroll
            for (int d = 1; d <= 8; d <<= 1) sum += __shfl_xor(sum, d, 64);
            float inv = 1.f / sum;
            #pragma unroll
            for (int nt = 0; nt < 8; ++nt) accs[mt][nt][r] *= inv;
        }
    }
    __syncthreads();
    #pragma unroll
    for (int mt = 0; mt < 2; ++mt)
        #pragma unroll
        for (int nt = 0; nt < 8; ++nt)
            #pragma unroll
            for (int r = 0; r < 4; ++r) {
                int h1 = (wv*2 + mt)*16 + quad*4 + r;
                int h2 = nt*16 + col;
                sh.a[h1][h2] = f2bf(accs[mt][nt][r]);
            }
    __syncthreads();

    const u16* vvs = ws + WS_VT + ((u32)(b*W_ + w))*65536u;   // [cc][h2], 512 rows x 128
    u16* cvout = ws + WS_CV + (u32)(b*C_)*HW_ + (u32)w*H_;    // + cc*HW + h1
    for (int mp = 0; mp < 4; ++mp) {
        f32x4 accv[2][8];
        #pragma unroll
        for (int mi = 0; mi < 2; ++mi)
            #pragma unroll
            for (int nt = 0; nt < 8; ++nt) accv[mi][nt] = (f32x4){0.f,0.f,0.f,0.f};
        #pragma unroll
        for (int ks = 0; ks < 4; ++ks) {
            bf16x8 bfv[8];
            #pragma unroll
            for (int nt = 0; nt < 8; ++nt)
                bfv[nt] = *reinterpret_cast<const bf16x8*>(&sh.a[nt*16 + col][ks*32 + quad*8]);
            #pragma unroll
            for (int mi = 0; mi < 2; ++mi) {
                int ccrow = mp*128 + wv*32 + mi*16 + col;
                bf16x8 af = *reinterpret_cast<const bf16x8*>(&vvs[(u32)ccrow*128u + ks*32 + quad*8]);
                #pragma unroll
                for (int nt = 0; nt < 8; ++nt)
                    accv[mi][nt] = __builtin_amdgcn_mfma_f32_16x16x32_bf16(af, bfv[nt], accv[mi][nt], 0, 0, 0);
            }
        }
        #pragma unroll
        for (int mi = 0; mi < 2; ++mi)
            #pragma unroll
            for (int nt = 0; nt < 8; ++nt)
                #pragma unroll
                for (int r = 0; r < 4; ++r) {
                    int cc = mp*128 + wv*32 + mi*16 + quad*4 + r;
                    int h1 = nt*16 + col;
                    cvout[(u32)cc*HW_ + h1] = f2bf(accv[mi][nt][r]);
                }
    }
}

// ---------------------------------------------------------------------------
// combine: out = gamma*(ch + cv) + x ; ch f32 in d_out, cv bf16 [b][c][w][h] in ws
// Vectorized: uint4 cv loads transposed into LDS; float4 ch/x loads + stores.
// ---------------------------------------------------------------------------
__global__ __launch_bounds__(256) void combine_kernel(const u16* __restrict__ ws, const float* __restrict__ x,
                                                      const float* __restrict__ gamma, float* __restrict__ outp)
{
    __shared__ u16 tl[64][70];   // [h][w]
    const int t = threadIdx.x;
    const int tile = blockIdx.x, cc = blockIdx.y, b = blockIdx.z;
    const int h0 = (tile >> 1) * 64, w0 = (tile & 1) * 64;
    const float g = gamma[0];
    const u32 base = ((u32)(b*C_) + cc) * HW_;
    const u16* cvs = ws + WS_CV + base;   // [w][h]
    #pragma unroll
    for (int pass = 0; pass < 2; ++pass) {
        int ci = pass*256 + t, wl = ci >> 3, h8 = ci & 7;
        uint4 d = *reinterpret_cast<const uint4*>(cvs + (u32)(w0+wl)*H_ + h0 + h8*8);
        const u16* e = reinterpret_cast<const u16*>(&d);
        #pragma unroll
        for (int j = 0; j < 8; ++j) tl[h8*8+j][wl] = e[j];
    }
    __syncthreads();
    #pragma unroll
    for (int pass = 0; pass < 4; ++pass) {
        int ci = pass*256 + t, hl = ci >> 4, w4 = ci & 15;
        u32 idx = base + (u32)(h0+hl)*W_ + w0 + w4*4;
        u32 p0 = *reinterpret_cast<const u32*>(&tl[hl][w4*4]);
        u32 p1 = *reinterpret_cast<const u32*>(&tl[hl][w4*4+2]);
        float4 ch = *reinterpret_cast<const float4*>(outp + idx);
        float4 xx = *reinterpret_cast<const float4*>(x + idx);
        float4 o;
        o.x = g*(ch.x + bf2f((u16)p0))         + xx.x;
        o.y = g*(ch.y + bf2f((u16)(p0 >> 16))) + xx.y;
        o.z = g*(ch.z + bf2f((u16)p1))         + xx.z;
        o.w = g*(ch.w + bf2f((u16)(p1 >> 16))) + xx.w;
        *reinterpret_cast<float4*>(outp + idx) = o;
    }
}

extern "C" void kernel_launch(void* const* d_in, const int* in_sizes, int n_in,
                              void* d_out, int out_size, void* d_ws, size_t ws_size,
                              hipStream_t stream)
{
    const float* x  = (const float*)d_in[0];
    const float* Wq = (const float*)d_in[1];
    const float* bq = (const float*)d_in[2];
    const float* Wk = (const float*)d_in[3];
    const float* bk = (const float*)d_in[4];
    const float* Wv = (const float*)d_in[5];
    const float* bv = (const float*)d_in[6];
    const float* gm = (const float*)d_in[7];
    float* out = (float*)d_out;
    u16* ws  = (u16*)d_ws;

    prep_x<<<dim3(256, 8, 4), 256, 0, stream>>>(x, ws);
    prep_w<<<dim3(320), 256, 0, stream>>>(Wq, Wk, Wv, ws);
    proj_kernel<<<dim3(2560), 256, 0, stream>>>(bq, bk, bv, ws);
    transpose_qk<<<dim3(4, 512), 256, 0, stream>>>(ws);
    shuffle_v<<<dim3(4, 128, 4), 256, 0, stream>>>(ws);
    hattn_kernel<<<dim3(128, 4), 256, 0, stream>>>(ws, out);
    vattn_kernel<<<dim3(128, 4), 256, 0, stream>>>(ws);
    combine_kernel<<<dim3(4, 512, 4), 256, 0, stream>>>(ws, x, gm, out);
}

// Round 5
// 629.711 us; speedup vs baseline: 1.1439x; 1.1439x over previous
//
#include <hip/hip_runtime.h>
#include <stdint.h>

#define B_ 4
#define C_ 512
#define CQ_ 64
#define H_ 128
#define W_ 128
#define HW_ 16384

typedef unsigned short u16;
typedef unsigned int u32;
typedef __attribute__((ext_vector_type(8))) __bf16 bf16x8;
typedef __attribute__((ext_vector_type(4))) float f32x4;

__device__ __forceinline__ u16 f2bf(float f) {
    u32 v; __builtin_memcpy(&v, &f, 4);
    v = (v + 0x7FFFu + ((v >> 16) & 1u)) >> 16;
    return (u16)v;
}
__device__ __forceinline__ float bf2f(u16 a) {
    u32 v = ((u32)a) << 16; float f; __builtin_memcpy(&f, &v, 4); return f;
}

// ---- workspace map (u16 elements), total 117,440,512 elems = 234,881,024 B ----
// XT (x^T bf16, [b][p][c]) dies after proj; CV reuses its space (vattn runs later).
// WB (W bf16) dies after proj; QT region (written by transpose_qk, post-proj) reuses it.
// WS_VT holds VV[b][w][cc][h2]: the vertical-attention V operand pre-arranged so
// each vattn MFMA A-fragment (8 consecutive h2 at fixed cc) is one contiguous 16B load.
#define WS_XT  0u
#define WS_CV  0u
#define WS_Q   33554432u
#define WS_K   37748736u
#define WS_V   41943040u   // layout [b][h][c][w]
#define WS_QT  75497472u
#define WS_KT  79691776u
#define WS_WB  75497472u   // aliases QT
#define WS_VT  83886080u   // layout [b][w][cc][h2], cc=(c&3)*128+h, h2=c>>2

// ---------------------------------------------------------------------------
// prep_x: x f32 [b][c][p] -> XT bf16 [b][p][c]   (convert once + transpose)
// ---------------------------------------------------------------------------
__global__ __launch_bounds__(256) void prep_x(const float* __restrict__ x, u16* __restrict__ ws)
{
    __shared__ __align__(16) u16 tl[64][72];
    const int t = threadIdx.x;
    const int pt = blockIdx.x, ct = blockIdx.y, b = blockIdx.z;
    const int p0 = pt * 64, c0 = ct * 64;
    const float* xb = x + ((u32)(b*C_ + c0))*HW_ + p0;
    #pragma unroll
    for (int pass = 0; pass < 4; ++pass) {
        int ci = pass*256 + t, cl = ci >> 4, p4 = ci & 15;
        float4 d = *reinterpret_cast<const float4*>(xb + (u32)cl*HW_ + p4*4);
        tl[p4*4+0][cl] = f2bf(d.x); tl[p4*4+1][cl] = f2bf(d.y);
        tl[p4*4+2][cl] = f2bf(d.z); tl[p4*4+3][cl] = f2bf(d.w);
    }
    __syncthreads();
    u16* dst = ws + WS_XT + ((u32)((b<<14) + p0))*512 + c0;
    #pragma unroll
    for (int pass = 0; pass < 2; ++pass) {
        int ci = pass*256 + t, pr = ci >> 3, k8 = ci & 7;
        uint4 d = *reinterpret_cast<const uint4*>(&tl[pr][k8*8]);
        *reinterpret_cast<uint4*>(dst + (u32)pr*512 + k8*8) = d;
    }
}

// ---------------------------------------------------------------------------
// prep_w: concat [Wq;Wk;Wv] f32 -> WB bf16 [640][512]. grid 320, 256 thr.
// ---------------------------------------------------------------------------
__global__ __launch_bounds__(256) void prep_w(const float* __restrict__ Wq, const float* __restrict__ Wk,
                                              const float* __restrict__ Wv, u16* __restrict__ ws)
{
    const int f = (blockIdx.x*256 + threadIdx.x)*4;
    const float* src;
    if (f < 32768)      src = Wq + f;
    else if (f < 65536) src = Wk + (f - 32768);
    else                src = Wv + (f - 65536);
    float4 d = *reinterpret_cast<const float4*>(src);
    u16 e[4] = { f2bf(d.x), f2bf(d.y), f2bf(d.z), f2bf(d.w) };
    *reinterpret_cast<uint2*>(ws + WS_WB + f) = *reinterpret_cast<const uint2*>(e);
}

// ---------------------------------------------------------------------------
// proj: D[o][p] = sum_c WB[o][c]*xT[p][c] (+bias). 128x128 tile, BK=64.
// Grid (128 bn, 4 b) = 512 blocks; the 5 m-tiles of a panel are an IN-BLOCK
// loop (bm=0..4). The XT pixel-panel is re-read by the SAME CU -> guaranteed
// XCD-local L2/L3 hits (replaces R3/R4's dispatch-swizzle, which exploded
// WRITE_SIZE 82->470 MB; staging/epilogue here are R2-verbatim, the last
// known-good write pattern). q,k -> [b][cq][hw]; v -> [b][h][c][w].
// ---------------------------------------------------------------------------
__global__ __launch_bounds__(256) void proj_kernel(const float* __restrict__ bq, const float* __restrict__ bk,
                                                   const float* __restrict__ bv, u16* __restrict__ ws)
{
    __shared__ __align__(16) u16 As[128][72];
    __shared__ __align__(16) u16 Bs[128][72];
    const int t = threadIdx.x;
    const int bn = blockIdx.x, b = blockIdx.y;
    const int p0 = bn*128;
    const u16* WB = ws + WS_WB;
    const u16* XT = ws + WS_XT + ((u32)((b<<14) + p0))*512;
    const int wv = t >> 6, ln = t & 63, quad = ln >> 4, col = ln & 15;
    const int mh = (wv>>1)*64, nh = (wv&1)*64;
    const int h = bn;

    #pragma unroll 1
    for (int bm = 0; bm < 5; ++bm) {
        const int m0 = bm*128;

        f32x4 acc[4][4];
        #pragma unroll
        for (int mt = 0; mt < 4; ++mt)
            #pragma unroll
            for (int nt = 0; nt < 4; ++nt) acc[mt][nt] = (f32x4){0.f,0.f,0.f,0.f};

        for (int c0 = 0; c0 < 512; c0 += 64) {
            #pragma unroll
            for (int pass = 0; pass < 4; ++pass) {
                int ci = pass*256 + t, row = ci >> 3, k8 = ci & 7;
                uint4 da = *reinterpret_cast<const uint4*>(WB + (u32)(m0+row)*512 + c0 + k8*8);
                *reinterpret_cast<uint4*>(&As[row][k8*8]) = da;
                uint4 db = *reinterpret_cast<const uint4*>(XT + (u32)row*512 + c0 + k8*8);
                *reinterpret_cast<uint4*>(&Bs[row][k8*8]) = db;
            }
            __syncthreads();
            #pragma unroll
            for (int ks = 0; ks < 2; ++ks) {
                const int kk = ks*32 + quad*8;
                bf16x8 am[4], bn_[4];
                #pragma unroll
                for (int mt = 0; mt < 4; ++mt) am[mt]  = *reinterpret_cast<const bf16x8*>(&As[mh + mt*16 + col][kk]);
                #pragma unroll
                for (int nt = 0; nt < 4; ++nt) bn_[nt] = *reinterpret_cast<const bf16x8*>(&Bs[nh + nt*16 + col][kk]);
                #pragma unroll
                for (int mt = 0; mt < 4; ++mt)
                    #pragma unroll
                    for (int nt = 0; nt < 4; ++nt)
                        acc[mt][nt] = __builtin_amdgcn_mfma_f32_16x16x32_bf16(am[mt], bn_[nt], acc[mt][nt], 0, 0, 0);
            }
            __syncthreads();
        }
        #pragma unroll
        for (int mt = 0; mt < 4; ++mt) {
            const int obase = m0 + mh + mt*16 + quad*4;
            #pragma unroll
            for (int r = 0; r < 4; ++r) {
                const int o = obase + r;
                float bb; u16* dst;
                if (o < 64)       { bb = bq[o];     dst = ws + WS_Q + ((u32)((b<<6) + o))*HW_ + p0; }
                else if (o < 128) { bb = bk[o-64];  dst = ws + WS_K + ((u32)((b<<6) + (o-64)))*HW_ + p0; }
                else              { bb = bv[o-128]; dst = ws + WS_V + (u32)b*8388608u + (u32)h*65536u + (u32)(o-128)*128u; }
                #pragma unroll
                for (int nt = 0; nt < 4; ++nt) {
                    int pl = nh + nt*16 + col;
                    dst[pl] = f2bf(acc[mt][nt][r] + bb);
                }
            }
        }
    }
}

// ---------------------------------------------------------------------------
// transpose_qk: 512 images (q then k, contiguous) [h][w] -> [w][h]
// Vectorized: uint4 global loads (8 u16/lane), LDS scatter-transpose,
// uint2 (4 u16) global stores. LDS stride 70 u16 (35 dwords, odd) ->
// phase-1 writes 4-way, phase-2 u32 reads 2-way (free).
// ---------------------------------------------------------------------------
__global__ __launch_bounds__(256) void transpose_qk(u16* __restrict__ ws)
{
    __shared__ u16 tl[64][70];   // [w][h]
    const int t = threadIdx.x;
    const int tile = blockIdx.x, img = blockIdx.y;
    const int h0 = (tile >> 1) * 64, w0 = (tile & 1) * 64;
    const u16* src = ws + WS_Q + (u32)img * HW_;
    u16* dst = ws + WS_QT + (u32)img * HW_;
    #pragma unroll
    for (int pass = 0; pass < 2; ++pass) {
        int ci = pass*256 + t, hl = ci >> 3, w8 = ci & 7;
        uint4 d = *reinterpret_cast<const uint4*>(src + (u32)(h0+hl)*W_ + w0 + w8*8);
        const u16* e = reinterpret_cast<const u16*>(&d);
        #pragma unroll
        for (int j = 0; j < 8; ++j) tl[w8*8+j][hl] = e[j];
    }
    __syncthreads();
    #pragma unroll
    for (int pass = 0; pass < 4; ++pass) {
        int ci = pass*256 + t, wl = ci >> 4, h4 = ci & 15;
        uint2 d;
        d.x = *reinterpret_cast<const u32*>(&tl[wl][h4*4]);
        d.y = *reinterpret_cast<const u32*>(&tl[wl][h4*4+2]);
        *reinterpret_cast<uint2*>(dst + (u32)(w0+wl)*H_ + h0 + h4*4) = d;
    }
}

// ---------------------------------------------------------------------------
// shuffle_v: V [b][h][c][w] -> VV [b][w][cc][h2], cc=(c&3)*128+h, h2=c>>2.
// Stored so vattn's MFMA A-fragments (8 consecutive h2, fixed cc) are single
// contiguous 16B global loads (mirrors hattn's direct-from-global V access).
// ---------------------------------------------------------------------------
__global__ __launch_bounds__(256) void shuffle_v(u16* __restrict__ ws)
{
    __shared__ u16 tl[128][134];   // [c_local][w], stride 134 u16 = 67 dw (odd)
    const int t = threadIdx.x;
    const int ct = blockIdx.x, h = blockIdx.y, b = blockIdx.z;
    const int c0 = ct * 128;
    const u16* src = ws + WS_V + (u32)b*8388608u + (u32)h*65536u + (u32)c0*128u;
    #pragma unroll
    for (int pass = 0; pass < 8; ++pass) {
        int ci = pass*256 + t, cl = ci >> 4, w8 = ci & 15;
        uint4 d = *reinterpret_cast<const uint4*>(src + (u32)cl*128u + w8*8);
        *reinterpret_cast<uint4*>(&tl[cl][w8*8]) = d;
    }
    __syncthreads();
    u16* dst = ws + WS_VT + (u32)b*8388608u;
    #pragma unroll
    for (int pass = 0; pass < 8; ++pass) {
        int ci = pass*256 + t;               // [0,2048)
        int w = ci >> 4, g = (ci >> 2) & 3, q4 = ci & 3;
        u16 e[8];
        #pragma unroll
        for (int jj = 0; jj < 8; ++jj)
            e[jj] = tl[4*(q4*8 + jj) + g][w];
        *reinterpret_cast<uint4*>(dst + (u32)w*65536u + (u32)(g*128 + h)*128u + (c0>>2) + q4*8)
            = *reinterpret_cast<const uint4*>(e);
    }
}

// shared LDS for hattn: q/k staging overlapped with softmaxed A
union __align__(16) ShAttn {
    struct QK { u16 q[128][72]; u16 kt[128][72]; } qk;  // 36864 B
    u16 a[128][136];                                    // 34816 B
};

// ---------------------------------------------------------------------------
// hattn: one block per (b,h). S[w1][w2]=sum_i q[w1][i]*kh[i][w2],
// kh[i][w2] = k[w2&63][2i+(w2>>6)].  ch[cc][w1]=sum_w2 A[w1][w2]*v[cc][w2].
// V in [b][h][c][w] -> A-operand fragments are 16B global loads within 4 KB.
// Writes raw ch (f32) -> d_out.
// ---------------------------------------------------------------------------
__global__ __launch_bounds__(256) void hattn_kernel(const u16* __restrict__ ws, float* __restrict__ outp)
{
    __shared__ ShAttn sh;
    const int t = threadIdx.x;
    const int h = blockIdx.x, b = blockIdx.y;
    const u16* qsrc = ws + WS_Q + (u32)(b*CQ_)*HW_ + h*W_;
    const u16* ksrc = ws + WS_K + (u32)(b*CQ_)*HW_ + h*W_;

    for (int e = t; e < 8192; e += 256) {
        int cq = e >> 7, w = e & 127;
        sh.qk.q[w][cq] = qsrc[cq*HW_ + w];
        u16 kv = ksrc[cq*HW_ + w];
        sh.qk.kt[cq + ((w & 1) << 6)][w >> 1] = kv;   // kt[w2][i] = kh[i][w2]
    }
    __syncthreads();

    const int wv = t >> 6, ln = t & 63, quad = ln >> 4, col = ln & 15;
    f32x4 accs[2][8];
    #pragma unroll
    for (int mt = 0; mt < 2; ++mt)
        #pragma unroll
        for (int nt = 0; nt < 8; ++nt) accs[mt][nt] = (f32x4){0.f,0.f,0.f,0.f};

    #pragma unroll
    for (int ks = 0; ks < 2; ++ks) {
        bf16x8 bfv[8];
        #pragma unroll
        for (int nt = 0; nt < 8; ++nt)
            bfv[nt] = *reinterpret_cast<const bf16x8*>(&sh.qk.kt[nt*16 + col][ks*32 + quad*8]);
        #pragma unroll
        for (int mt = 0; mt < 2; ++mt) {
            bf16x8 af = *reinterpret_cast<const bf16x8*>(&sh.qk.q[(wv*2 + mt)*16 + col][ks*32 + quad*8]);
            #pragma unroll
            for (int nt = 0; nt < 8; ++nt)
                accs[mt][nt] = __builtin_amdgcn_mfma_f32_16x16x32_bf16(af, bfv[nt], accs[mt][nt], 0, 0, 0);
        }
    }
    #pragma unroll
    for (int mt = 0; mt < 2; ++mt) {
        #pragma unroll
        for (int r = 0; r < 4; ++r) {
            float mx = accs[mt][0][r];
            #pragma unroll
            for (int nt = 1; nt < 8; ++nt) mx = fmaxf(mx, accs[mt][nt][r]);
            #pragma unroll
            for (int d = 1; d <= 8; d <<= 1) mx = fmaxf(mx, __shfl_xor(mx, d, 64));
            float sum = 0.f;
            #pragma unroll
            for (int nt = 0; nt < 8; ++nt) { float ev = __expf(accs[mt][nt][r] - mx); accs[mt][nt][r] = ev; sum += ev; }
            #pragma unroll
            for (int d = 1; d <= 8; d <<= 1) sum += __shfl_xor(sum, d, 64);
            float inv = 1.f / sum;
            #pragma unroll
            for (int nt = 0; nt < 8; ++nt) accs[mt][nt][r] *= inv;
        }
    }
    __syncthreads();
    #pragma unroll
    for (int mt = 0; mt < 2; ++mt)
        #pragma unroll
        for (int nt = 0; nt < 8; ++nt)
            #pragma unroll
            for (int r = 0; r < 4; ++r) {
                int w1 = (wv*2 + mt)*16 + quad*4 + r;
                int w2 = nt*16 + col;
                sh.a[w1][w2] = f2bf(accs[mt][nt][r]);
            }
    __syncthreads();

    const u16* vsrc = ws + WS_V + (u32)b*8388608u + (u32)h*65536u;   // [c][w], rows 128
    float* chout = outp + (u32)(b*C_)*HW_ + h*W_;
    const int ccw = wv * 128;
    for (int mp = 0; mp < 4; ++mp) {
        f32x4 accv[2][8];
        #pragma unroll
        for (int mi = 0; mi < 2; ++mi)
            #pragma unroll
            for (int nt = 0; nt < 8; ++nt) accv[mi][nt] = (f32x4){0.f,0.f,0.f,0.f};
        #pragma unroll
        for (int ks = 0; ks < 4; ++ks) {
            bf16x8 bfv[8];
            #pragma unroll
            for (int nt = 0; nt < 8; ++nt)
                bfv[nt] = *reinterpret_cast<const bf16x8*>(&sh.a[nt*16 + col][ks*32 + quad*8]);
            #pragma unroll
            for (int mi = 0; mi < 2; ++mi) {
                int cct = ccw + (mp*2 + mi)*16;
                bf16x8 af = *reinterpret_cast<const bf16x8*>(&vsrc[(u32)(cct + col)*128u + ks*32 + quad*8]);
                #pragma unroll
                for (int nt = 0; nt < 8; ++nt)
                    accv[mi][nt] = __builtin_amdgcn_mfma_f32_16x16x32_bf16(af, bfv[nt], accv[mi][nt], 0, 0, 0);
            }
        }
        #pragma unroll
        for (int mi = 0; mi < 2; ++mi)
            #pragma unroll
            for (int nt = 0; nt < 8; ++nt)
                #pragma unroll
                for (int r = 0; r < 4; ++r) {
                    int cc = ccw + (mp*2 + mi)*16 + quad*4 + r;
                    int w1 = nt*16 + col;
                    chout[(u32)cc*HW_ + w1] = accv[mi][nt][r];
                }
    }
}

// LDS for vattn: qk staging / softmaxed A (V read direct from global VV)
union __align__(16) ShV {
    struct QK { u16 q[128][72]; u16 kt[128][72]; } qk;  // 36864 B
    u16 a[128][136];                                    // 34816 B
};

// ---------------------------------------------------------------------------
// vattn: one block per (b,w). qv[h1][i]=qT[h1>>1][w][64*(h1&1)+i];
// kv[i][h2]=kT[i][w][h2]; vv[h2][cc]=VV[b][w][cc][h2] (pre-arranged by
// shuffle_v) -> A-operand fragments are contiguous 16B global loads; no V
// staging, no per-chunk barriers.
// Writes cv^T [b][cc][w][h1] bf16 -> WS_CV.
// ---------------------------------------------------------------------------
__global__ __launch_bounds__(256) void vattn_kernel(u16* __restrict__ ws)
{
    __shared__ ShV sh;
    const int t = threadIdx.x;
    const int w = blockIdx.x, b = blockIdx.y;
    const u16* qTs = ws + WS_QT + (u32)(b*CQ_)*HW_ + w*H_;
    const u16* kTs = ws + WS_KT + (u32)(b*CQ_)*HW_ + w*H_;

    for (int e = t; e < 8192; e += 256) {
        int cq = e >> 7, hh = e & 127;
        sh.qk.q[2*cq + (hh >> 6)][hh & 63] = qTs[cq*HW_ + hh];
        sh.qk.kt[hh][cq] = kTs[cq*HW_ + hh];
    }
    __syncthreads();

    const int wv = t >> 6, ln = t & 63, quad = ln >> 4, col = ln & 15;
    f32x4 accs[2][8];
    #pragma unroll
    for (int mt = 0; mt < 2; ++mt)
        #pragma unroll
        for (int nt = 0; nt < 8; ++nt) accs[mt][nt] = (f32x4){0.f,0.f,0.f,0.f};

    #pragma unroll
    for (int ks = 0; ks < 2; ++ks) {
        bf16x8 bfv[8];
        #pragma unroll
        for (int nt = 0; nt < 8; ++nt)
            bfv[nt] = *reinterpret_cast<const bf16x8*>(&sh.qk.kt[nt*16 + col][ks*32 + quad*8]);
        #pragma unroll
        for (int mt = 0; mt < 2; ++mt) {
            bf16x8 af = *reinterpret_cast<const bf16x8*>(&sh.qk.q[(wv*2 + mt)*16 + col][ks*32 + quad*8]);
            #pragma unroll
            for (int nt = 0; nt < 8; ++nt)
                accs[mt][nt] = __builtin_amdgcn_mfma_f32_16x16x32_bf16(af, bfv[nt], accs[mt][nt], 0, 0, 0);
        }
    }
    #pragma unroll
    for (int mt = 0; mt < 2; ++mt) {
        #pragma unroll
        for (int r = 0; r < 4; ++r) {
            float mx = accs[mt][0][r];
            #pragma unroll
            for (int nt = 1; nt < 8; ++nt) mx = fmaxf(mx, accs[mt][nt][r]);
            #pragma unroll
            for (int d = 1; d <= 8; d <<= 1) mx = fmaxf(mx, __shfl_xor(mx, d, 64));
            float sum = 0.f;
            #pragma unroll
            for (int nt = 0; nt < 8; ++nt) { float ev = __expf(accs[mt][nt][r] - mx); accs[mt][nt][r] = ev; sum += ev; }
            #pragma unroll
            for (int d = 1; d <= 8; d <<= 1) sum += __shfl_xor(sum, d, 64);
            float inv = 1.f / sum;
            #pragma unroll
            for (int nt = 0; nt < 8; ++nt) accs[mt][nt][r] *= inv;
        }
    }
    __syncthreads();
    #pragma unroll
    for (int mt = 0; mt < 2; ++mt)
        #pragma unroll
        for (int nt = 0; nt < 8; ++nt)
            #pragma unroll
            for (int r = 0; r < 4; ++r) {
                int h1 = (wv*2 + mt)*16 + quad*4 + r;
                int h2 = nt*16 + col;
                sh.a[h1][h2] = f2bf(accs[mt][nt][r]);
            }
    __syncthreads();

    const u16* vvs = ws + WS_VT + ((u32)(b*W_ + w))*65536u;   // [cc][h2], 512 rows x 128
    u16* cvout = ws + WS_CV + (u32)(b*C_)*HW_ + (u32)w*H_;    // + cc*HW + h1
    for (int mp = 0; mp < 4; ++mp) {
        f32x4 accv[2][8];
        #pragma unroll
        for (int mi = 0; mi < 2; ++mi)
            #pragma unroll
            for (int nt = 0; nt < 8; ++nt) accv[mi][nt] = (f32x4){0.f,0.f,0.f,0.f};
        #pragma unroll
        for (int ks = 0; ks < 4; ++ks) {
            bf16x8 bfv[8];
            #pragma unroll
            for (int nt = 0; nt < 8; ++nt)
                bfv[nt] = *reinterpret_cast<const bf16x8*>(&sh.a[nt*16 + col][ks*32 + quad*8]);
            #pragma unroll
            for (int mi = 0; mi < 2; ++mi) {
                int ccrow = mp*128 + wv*32 + mi*16 + col;
                bf16x8 af = *reinterpret_cast<const bf16x8*>(&vvs[(u32)ccrow*128u + ks*32 + quad*8]);
                #pragma unroll
                for (int nt = 0; nt < 8; ++nt)
                    accv[mi][nt] = __builtin_amdgcn_mfma_f32_16x16x32_bf16(af, bfv[nt], accv[mi][nt], 0, 0, 0);
            }
        }
        #pragma unroll
        for (int mi = 0; mi < 2; ++mi)
            #pragma unroll
            for (int nt = 0; nt < 8; ++nt)
                #pragma unroll
                for (int r = 0; r < 4; ++r) {
                    int cc = mp*128 + wv*32 + mi*16 + quad*4 + r;
                    int h1 = nt*16 + col;
                    cvout[(u32)cc*HW_ + h1] = f2bf(accv[mi][nt][r]);
                }
    }
}

// ---------------------------------------------------------------------------
// combine: out = gamma*(ch + cv) + x ; ch f32 in d_out, cv bf16 [b][c][w][h] in ws
// Vectorized: uint4 cv loads transposed into LDS; float4 ch/x loads + stores.
// ---------------------------------------------------------------------------
__global__ __launch_bounds__(256) void combine_kernel(const u16* __restrict__ ws, const float* __restrict__ x,
                                                      const float* __restrict__ gamma, float* __restrict__ outp)
{
    __shared__ u16 tl[64][70];   // [h][w]
    const int t = threadIdx.x;
    const int tile = blockIdx.x, cc = blockIdx.y, b = blockIdx.z;
    const int h0 = (tile >> 1) * 64, w0 = (tile & 1) * 64;
    const float g = gamma[0];
    const u32 base = ((u32)(b*C_) + cc) * HW_;
    const u16* cvs = ws + WS_CV + base;   // [w][h]
    #pragma unroll
    for (int pass = 0; pass < 2; ++pass) {
        int ci = pass*256 + t, wl = ci >> 3, h8 = ci & 7;
        uint4 d = *reinterpret_cast<const uint4*>(cvs + (u32)(w0+wl)*H_ + h0 + h8*8);
        const u16* e = reinterpret_cast<const u16*>(&d);
        #pragma unroll
        for (int j = 0; j < 8; ++j) tl[h8*8+j][wl] = e[j];
    }
    __syncthreads();
    #pragma unroll
    for (int pass = 0; pass < 4; ++pass) {
        int ci = pass*256 + t, hl = ci >> 4, w4 = ci & 15;
        u32 idx = base + (u32)(h0+hl)*W_ + w0 + w4*4;
        u32 p0 = *reinterpret_cast<const u32*>(&tl[hl][w4*4]);
        u32 p1 = *reinterpret_cast<const u32*>(&tl[hl][w4*4+2]);
        float4 ch = *reinterpret_cast<const float4*>(outp + idx);
        float4 xx = *reinterpret_cast<const float4*>(x + idx);
        float4 o;
        o.x = g*(ch.x + bf2f((u16)p0))         + xx.x;
        o.y = g*(ch.y + bf2f((u16)(p0 >> 16))) + xx.y;
        o.z = g*(ch.z + bf2f((u16)p1))         + xx.z;
        o.w = g*(ch.w + bf2f((u16)(p1 >> 16))) + xx.w;
        *reinterpret_cast<float4*>(outp + idx) = o;
    }
}

extern "C" void kernel_launch(void* const* d_in, const int* in_sizes, int n_in,
                              void* d_out, int out_size, void* d_ws, size_t ws_size,
                              hipStream_t stream)
{
    const float* x  = (const float*)d_in[0];
    const float* Wq = (const float*)d_in[1];
    const float* bq = (const float*)d_in[2];
    const float* Wk = (const float*)d_in[3];
    const float* bk = (const float*)d_in[4];
    const float* Wv = (const float*)d_in[5];
    const float* bv = (const float*)d_in[6];
    const float* gm = (const float*)d_in[7];
    float* out = (float*)d_out;
    u16* ws  = (u16*)d_ws;

    prep_x<<<dim3(256, 8, 4), 256, 0, stream>>>(x, ws);
    prep_w<<<dim3(320), 256, 0, stream>>>(Wq, Wk, Wv, ws);
    proj_kernel<<<dim3(128, 4), 256, 0, stream>>>(bq, bk, bv, ws);
    transpose_qk<<<dim3(4, 512), 256, 0, stream>>>(ws);
    shuffle_v<<<dim3(4, 128, 4), 256, 0, stream>>>(ws);
    hattn_kernel<<<dim3(128, 4), 256, 0, stream>>>(ws, out);
    vattn_kernel<<<dim3(128, 4), 256, 0, stream>>>(ws);
    combine_kernel<<<dim3(4, 512, 4), 256, 0, stream>>>(ws, x, gm, out);
}

// Round 6
// 579.345 us; speedup vs baseline: 1.2433x; 1.0869x over previous
//
#include <hip/hip_runtime.h>
#include <stdint.h>

#define B_ 4
#define C_ 512
#define CQ_ 64
#define H_ 128
#define W_ 128
#define HW_ 16384

typedef unsigned short u16;
typedef unsigned int u32;
typedef __attribute__((ext_vector_type(8))) __bf16 bf16x8;
typedef __attribute__((ext_vector_type(4))) float f32x4;

__device__ __forceinline__ u16 f2bf(float f) {
    u32 v; __builtin_memcpy(&v, &f, 4);
    v = (v + 0x7FFFu + ((v >> 16) & 1u)) >> 16;
    return (u16)v;
}
__device__ __forceinline__ float bf2f(u16 a) {
    u32 v = ((u32)a) << 16; float f; __builtin_memcpy(&f, &v, 4); return f;
}

// ---- workspace map (u16 elements), total 117,440,512 elems = 234,881,024 B ----
// XT (x^T bf16, [b][p][c]) dies after proj; CV reuses its space (vattn runs later).
// WB (W bf16) dies after proj; QT region (written by transpose_qk, post-proj) reuses it.
// WS_VT holds VV[b][w][cc][h2]: the vertical-attention V operand pre-arranged so
// each vattn MFMA A-fragment (8 consecutive h2 at fixed cc) is one contiguous 16B load.
#define WS_XT  0u
#define WS_CV  0u
#define WS_Q   33554432u
#define WS_K   37748736u
#define WS_V   41943040u   // layout [b][h][c][w]
#define WS_QT  75497472u
#define WS_KT  79691776u
#define WS_WB  75497472u   // aliases QT
#define WS_VT  83886080u   // layout [b][w][cc][h2], cc=(c&3)*128+h, h2=c>>2

// ---------------------------------------------------------------------------
// prep_x: x f32 [b][c][p] -> XT bf16 [b][p][c]   (convert once + transpose)
// ---------------------------------------------------------------------------
__global__ __launch_bounds__(256) void prep_x(const float* __restrict__ x, u16* __restrict__ ws)
{
    __shared__ __align__(16) u16 tl[64][72];
    const int t = threadIdx.x;
    const int pt = blockIdx.x, ct = blockIdx.y, b = blockIdx.z;
    const int p0 = pt * 64, c0 = ct * 64;
    const float* xb = x + ((u32)(b*C_ + c0))*HW_ + p0;
    #pragma unroll
    for (int pass = 0; pass < 4; ++pass) {
        int ci = pass*256 + t, cl = ci >> 4, p4 = ci & 15;
        float4 d = *reinterpret_cast<const float4*>(xb + (u32)cl*HW_ + p4*4);
        tl[p4*4+0][cl] = f2bf(d.x); tl[p4*4+1][cl] = f2bf(d.y);
        tl[p4*4+2][cl] = f2bf(d.z); tl[p4*4+3][cl] = f2bf(d.w);
    }
    __syncthreads();
    u16* dst = ws + WS_XT + ((u32)((b<<14) + p0))*512 + c0;
    #pragma unroll
    for (int pass = 0; pass < 2; ++pass) {
        int ci = pass*256 + t, pr = ci >> 3, k8 = ci & 7;
        uint4 d = *reinterpret_cast<const uint4*>(&tl[pr][k8*8]);
        *reinterpret_cast<uint4*>(dst + (u32)pr*512 + k8*8) = d;
    }
}

// ---------------------------------------------------------------------------
// prep_w: concat [Wq;Wk;Wv] f32 -> WB bf16 [640][512]. grid 320, 256 thr.
// ---------------------------------------------------------------------------
__global__ __launch_bounds__(256) void prep_w(const float* __restrict__ Wq, const float* __restrict__ Wk,
                                              const float* __restrict__ Wv, u16* __restrict__ ws)
{
    const int f = (blockIdx.x*256 + threadIdx.x)*4;
    const float* src;
    if (f < 32768)      src = Wq + f;
    else if (f < 65536) src = Wk + (f - 32768);
    else                src = Wv + (f - 65536);
    float4 d = *reinterpret_cast<const float4*>(src);
    u16 e[4] = { f2bf(d.x), f2bf(d.y), f2bf(d.z), f2bf(d.w) };
    *reinterpret_cast<uint2*>(ws + WS_WB + f) = *reinterpret_cast<const uint2*>(e);
}

// ---------------------------------------------------------------------------
// proj: D[o][p] = sum_c WB[o][c]*xT[p][c] (+bias). 128x128 tile, BK=64.
// grid (5 bm, 128 bn(=h), 4 b) -- R2-verbatim (the best measured: 94 us,
// WRITE 82 MB). R3/R4's swizzle+prefetch exploded WRITE 5.8x; R5's in-block
// panel loop starved occupancy (2 blocks/CU). Plain grid wins.
// q,k -> [b][cq][hw]; v -> [b][h][c][w].
// ---------------------------------------------------------------------------
__global__ __launch_bounds__(256) void proj_kernel(const float* __restrict__ bq, const float* __restrict__ bk,
                                                   const float* __restrict__ bv, u16* __restrict__ ws)
{
    __shared__ __align__(16) u16 As[128][72];
    __shared__ __align__(16) u16 Bs[128][72];
    const int t = threadIdx.x;
    const int bm = blockIdx.x, bn = blockIdx.y, b = blockIdx.z;
    const int m0 = bm*128, p0 = bn*128;
    const u16* WB = ws + WS_WB;
    const u16* XT = ws + WS_XT + ((u32)((b<<14) + p0))*512;
    const int wv = t >> 6, ln = t & 63, quad = ln >> 4, col = ln & 15;
    const int mh = (wv>>1)*64, nh = (wv&1)*64;

    f32x4 acc[4][4];
    #pragma unroll
    for (int mt = 0; mt < 4; ++mt)
        #pragma unroll
        for (int nt = 0; nt < 4; ++nt) acc[mt][nt] = (f32x4){0.f,0.f,0.f,0.f};

    for (int c0 = 0; c0 < 512; c0 += 64) {
        #pragma unroll
        for (int pass = 0; pass < 4; ++pass) {
            int ci = pass*256 + t, row = ci >> 3, k8 = ci & 7;
            uint4 da = *reinterpret_cast<const uint4*>(WB + (u32)(m0+row)*512 + c0 + k8*8);
            *reinterpret_cast<uint4*>(&As[row][k8*8]) = da;
            uint4 db = *reinterpret_cast<const uint4*>(XT + (u32)row*512 + c0 + k8*8);
            *reinterpret_cast<uint4*>(&Bs[row][k8*8]) = db;
        }
        __syncthreads();
        #pragma unroll
        for (int ks = 0; ks < 2; ++ks) {
            const int kk = ks*32 + quad*8;
            bf16x8 am[4], bn_[4];
            #pragma unroll
            for (int mt = 0; mt < 4; ++mt) am[mt]  = *reinterpret_cast<const bf16x8*>(&As[mh + mt*16 + col][kk]);
            #pragma unroll
            for (int nt = 0; nt < 4; ++nt) bn_[nt] = *reinterpret_cast<const bf16x8*>(&Bs[nh + nt*16 + col][kk]);
            #pragma unroll
            for (int mt = 0; mt < 4; ++mt)
                #pragma unroll
                for (int nt = 0; nt < 4; ++nt)
                    acc[mt][nt] = __builtin_amdgcn_mfma_f32_16x16x32_bf16(am[mt], bn_[nt], acc[mt][nt], 0, 0, 0);
        }
        __syncthreads();
    }
    const int h = bn;
    #pragma unroll
    for (int mt = 0; mt < 4; ++mt) {
        const int obase = m0 + mh + mt*16 + quad*4;
        #pragma unroll
        for (int r = 0; r < 4; ++r) {
            const int o = obase + r;
            float bb; u16* dst;
            if (o < 64)       { bb = bq[o];     dst = ws + WS_Q + ((u32)((b<<6) + o))*HW_ + p0; }
            else if (o < 128) { bb = bk[o-64];  dst = ws + WS_K + ((u32)((b<<6) + (o-64)))*HW_ + p0; }
            else              { bb = bv[o-128]; dst = ws + WS_V + (u32)b*8388608u + (u32)h*65536u + (u32)(o-128)*128u; }
            #pragma unroll
            for (int nt = 0; nt < 4; ++nt) {
                int pl = nh + nt*16 + col;
                dst[pl] = f2bf(acc[mt][nt][r] + bb);
            }
        }
    }
}

// ---------------------------------------------------------------------------
// transpose_qk: 512 images (q then k, contiguous) [h][w] -> [w][h]
// ---------------------------------------------------------------------------
__global__ __launch_bounds__(256) void transpose_qk(u16* __restrict__ ws)
{
    __shared__ u16 tl[64][70];   // [w][h]
    const int t = threadIdx.x;
    const int tile = blockIdx.x, img = blockIdx.y;
    const int h0 = (tile >> 1) * 64, w0 = (tile & 1) * 64;
    const u16* src = ws + WS_Q + (u32)img * HW_;
    u16* dst = ws + WS_QT + (u32)img * HW_;
    #pragma unroll
    for (int pass = 0; pass < 2; ++pass) {
        int ci = pass*256 + t, hl = ci >> 3, w8 = ci & 7;
        uint4 d = *reinterpret_cast<const uint4*>(src + (u32)(h0+hl)*W_ + w0 + w8*8);
        const u16* e = reinterpret_cast<const u16*>(&d);
        #pragma unroll
        for (int j = 0; j < 8; ++j) tl[w8*8+j][hl] = e[j];
    }
    __syncthreads();
    #pragma unroll
    for (int pass = 0; pass < 4; ++pass) {
        int ci = pass*256 + t, wl = ci >> 4, h4 = ci & 15;
        uint2 d;
        d.x = *reinterpret_cast<const u32*>(&tl[wl][h4*4]);
        d.y = *reinterpret_cast<const u32*>(&tl[wl][h4*4+2]);
        *reinterpret_cast<uint2*>(dst + (u32)(w0+wl)*H_ + h0 + h4*4) = d;
    }
}

// ---------------------------------------------------------------------------
// shuffle_v: V [b][h][c][w] -> VV [b][w][cc][h2], cc=(c&3)*128+h, h2=c>>2.
// ---------------------------------------------------------------------------
__global__ __launch_bounds__(256) void shuffle_v(u16* __restrict__ ws)
{
    __shared__ u16 tl[128][134];   // [c_local][w], stride 134 u16 = 67 dw (odd)
    const int t = threadIdx.x;
    const int ct = blockIdx.x, h = blockIdx.y, b = blockIdx.z;
    const int c0 = ct * 128;
    const u16* src = ws + WS_V + (u32)b*8388608u + (u32)h*65536u + (u32)c0*128u;
    #pragma unroll
    for (int pass = 0; pass < 8; ++pass) {
        int ci = pass*256 + t, cl = ci >> 4, w8 = ci & 15;
        uint4 d = *reinterpret_cast<const uint4*>(src + (u32)cl*128u + w8*8);
        *reinterpret_cast<uint4*>(&tl[cl][w8*8]) = d;
    }
    __syncthreads();
    u16* dst = ws + WS_VT + (u32)b*8388608u;
    #pragma unroll
    for (int pass = 0; pass < 8; ++pass) {
        int ci = pass*256 + t;               // [0,2048)
        int w = ci >> 4, g = (ci >> 2) & 3, q4 = ci & 3;
        u16 e[8];
        #pragma unroll
        for (int jj = 0; jj < 8; ++jj)
            e[jj] = tl[4*(q4*8 + jj) + g][w];
        *reinterpret_cast<uint4*>(dst + (u32)w*65536u + (u32)(g*128 + h)*128u + (c0>>2) + q4*8)
            = *reinterpret_cast<const uint4*>(e);
    }
}

// shared LDS for both attention bodies: q/k staging overlapped with softmaxed A
union __align__(16) ShF {
    struct QK { u16 q[128][72]; u16 kt[128][72]; } qk;  // 36864 B
    u16 a[128][136];                                    // 34816 B
};

// ---------------------------------------------------------------------------
// hattn body: one block per (b,h). S[w1][w2]=sum_i q[w1][i]*kh[i][w2],
// kh[i][w2] = k[w2&63][2i+(w2>>6)].  ch[cc][w1]=sum_w2 A[w1][w2]*v[cc][w2].
// V in [b][h][c][w] -> A-operand fragments are 16B global loads within 4 KB.
// Writes raw ch (f32) -> d_out.
// ---------------------------------------------------------------------------
__device__ __forceinline__ void hattn_body(ShF& sh, const u16* __restrict__ ws, float* __restrict__ outp)
{
    const int t = threadIdx.x;
    const int h = blockIdx.x, b = blockIdx.y;
    const u16* qsrc = ws + WS_Q + (u32)(b*CQ_)*HW_ + h*W_;
    const u16* ksrc = ws + WS_K + (u32)(b*CQ_)*HW_ + h*W_;

    for (int e = t; e < 8192; e += 256) {
        int cq = e >> 7, w = e & 127;
        sh.qk.q[w][cq] = qsrc[cq*HW_ + w];
        u16 kv = ksrc[cq*HW_ + w];
        sh.qk.kt[cq + ((w & 1) << 6)][w >> 1] = kv;   // kt[w2][i] = kh[i][w2]
    }
    __syncthreads();

    const int wv = t >> 6, ln = t & 63, quad = ln >> 4, col = ln & 15;
    f32x4 accs[2][8];
    #pragma unroll
    for (int mt = 0; mt < 2; ++mt)
        #pragma unroll
        for (int nt = 0; nt < 8; ++nt) accs[mt][nt] = (f32x4){0.f,0.f,0.f,0.f};

    #pragma unroll
    for (int ks = 0; ks < 2; ++ks) {
        bf16x8 bfv[8];
        #pragma unroll
        for (int nt = 0; nt < 8; ++nt)
            bfv[nt] = *reinterpret_cast<const bf16x8*>(&sh.qk.kt[nt*16 + col][ks*32 + quad*8]);
        #pragma unroll
        for (int mt = 0; mt < 2; ++mt) {
            bf16x8 af = *reinterpret_cast<const bf16x8*>(&sh.qk.q[(wv*2 + mt)*16 + col][ks*32 + quad*8]);
            #pragma unroll
            for (int nt = 0; nt < 8; ++nt)
                accs[mt][nt] = __builtin_amdgcn_mfma_f32_16x16x32_bf16(af, bfv[nt], accs[mt][nt], 0, 0, 0);
        }
    }
    #pragma unroll
    for (int mt = 0; mt < 2; ++mt) {
        #pragma unroll
        for (int r = 0; r < 4; ++r) {
            float mx = accs[mt][0][r];
            #pragma unroll
            for (int nt = 1; nt < 8; ++nt) mx = fmaxf(mx, accs[mt][nt][r]);
            #pragma unroll
            for (int d = 1; d <= 8; d <<= 1) mx = fmaxf(mx, __shfl_xor(mx, d, 64));
            float sum = 0.f;
            #pragma unroll
            for (int nt = 0; nt < 8; ++nt) { float ev = __expf(accs[mt][nt][r] - mx); accs[mt][nt][r] = ev; sum += ev; }
            #pragma unroll
            for (int d = 1; d <= 8; d <<= 1) sum += __shfl_xor(sum, d, 64);
            float inv = 1.f / sum;
            #pragma unroll
            for (int nt = 0; nt < 8; ++nt) accs[mt][nt][r] *= inv;
        }
    }
    __syncthreads();
    #pragma unroll
    for (int mt = 0; mt < 2; ++mt)
        #pragma unroll
        for (int nt = 0; nt < 8; ++nt)
            #pragma unroll
            for (int r = 0; r < 4; ++r) {
                int w1 = (wv*2 + mt)*16 + quad*4 + r;
                int w2 = nt*16 + col;
                sh.a[w1][w2] = f2bf(accs[mt][nt][r]);
            }
    __syncthreads();

    const u16* vsrc = ws + WS_V + (u32)b*8388608u + (u32)h*65536u;   // [c][w], rows 128
    float* chout = outp + (u32)(b*C_)*HW_ + h*W_;
    const int ccw = wv * 128;
    for (int mp = 0; mp < 4; ++mp) {
        f32x4 accv[2][8];
        #pragma unroll
        for (int mi = 0; mi < 2; ++mi)
            #pragma unroll
            for (int nt = 0; nt < 8; ++nt) accv[mi][nt] = (f32x4){0.f,0.f,0.f,0.f};
        #pragma unroll
        for (int ks = 0; ks < 4; ++ks) {
            bf16x8 bfv[8];
            #pragma unroll
            for (int nt = 0; nt < 8; ++nt)
                bfv[nt] = *reinterpret_cast<const bf16x8*>(&sh.a[nt*16 + col][ks*32 + quad*8]);
            #pragma unroll
            for (int mi = 0; mi < 2; ++mi) {
                int cct = ccw + (mp*2 + mi)*16;
                bf16x8 af = *reinterpret_cast<const bf16x8*>(&vsrc[(u32)(cct + col)*128u + ks*32 + quad*8]);
                #pragma unroll
                for (int nt = 0; nt < 8; ++nt)
                    accv[mi][nt] = __builtin_amdgcn_mfma_f32_16x16x32_bf16(af, bfv[nt], accv[mi][nt], 0, 0, 0);
            }
        }
        #pragma unroll
        for (int mi = 0; mi < 2; ++mi)
            #pragma unroll
            for (int nt = 0; nt < 8; ++nt)
                #pragma unroll
                for (int r = 0; r < 4; ++r) {
                    int cc = ccw + (mp*2 + mi)*16 + quad*4 + r;
                    int w1 = nt*16 + col;
                    chout[(u32)cc*HW_ + w1] = accv[mi][nt][r];
                }
    }
}

// ---------------------------------------------------------------------------
// vattn body: one block per (b,w). qv[h1][i]=qT[h1>>1][w][64*(h1&1)+i];
// kv[i][h2]=kT[i][w][h2]; vv[h2][cc]=VV[b][w][cc][h2] (pre-arranged by
// shuffle_v) -> A-operand fragments are contiguous 16B global loads.
// Writes cv^T [b][cc][w][h1] bf16 -> WS_CV.
// ---------------------------------------------------------------------------
__device__ __forceinline__ void vattn_body(ShF& sh, u16* __restrict__ ws)
{
    const int t = threadIdx.x;
    const int w = blockIdx.x, b = blockIdx.y;
    const u16* qTs = ws + WS_QT + (u32)(b*CQ_)*HW_ + w*H_;
    const u16* kTs = ws + WS_KT + (u32)(b*CQ_)*HW_ + w*H_;

    for (int e = t; e < 8192; e += 256) {
        int cq = e >> 7, hh = e & 127;
        sh.qk.q[2*cq + (hh >> 6)][hh & 63] = qTs[cq*HW_ + hh];
        sh.qk.kt[hh][cq] = kTs[cq*HW_ + hh];
    }
    __syncthreads();

    const int wv = t >> 6, ln = t & 63, quad = ln >> 4, col = ln & 15;
    f32x4 accs[2][8];
    #pragma unroll
    for (int mt = 0; mt < 2; ++mt)
        #pragma unroll
        for (int nt = 0; nt < 8; ++nt) accs[mt][nt] = (f32x4){0.f,0.f,0.f,0.f};

    #pragma unroll
    for (int ks = 0; ks < 2; ++ks) {
        bf16x8 bfv[8];
        #pragma unroll
        for (int nt = 0; nt < 8; ++nt)
            bfv[nt] = *reinterpret_cast<const bf16x8*>(&sh.qk.kt[nt*16 + col][ks*32 + quad*8]);
        #pragma unroll
        for (int mt = 0; mt < 2; ++mt) {
            bf16x8 af = *reinterpret_cast<const bf16x8*>(&sh.qk.q[(wv*2 + mt)*16 + col][ks*32 + quad*8]);
            #pragma unroll
            for (int nt = 0; nt < 8; ++nt)
                accs[mt][nt] = __builtin_amdgcn_mfma_f32_16x16x32_bf16(af, bfv[nt], accs[mt][nt], 0, 0, 0);
        }
    }
    #pragma unroll
    for (int mt = 0; mt < 2; ++mt) {
        #pragma unroll
        for (int r = 0; r < 4; ++r) {
            float mx = accs[mt][0][r];
            #pragma unroll
            for (int nt = 1; nt < 8; ++nt) mx = fmaxf(mx, accs[mt][nt][r]);
            #pragma unroll
            for (int d = 1; d <= 8; d <<= 1) mx = fmaxf(mx, __shfl_xor(mx, d, 64));
            float sum = 0.f;
            #pragma unroll
            for (int nt = 0; nt < 8; ++nt) { float ev = __expf(accs[mt][nt][r] - mx); accs[mt][nt][r] = ev; sum += ev; }
            #pragma unroll
            for (int d = 1; d <= 8; d <<= 1) sum += __shfl_xor(sum, d, 64);
            float inv = 1.f / sum;
            #pragma unroll
            for (int nt = 0; nt < 8; ++nt) accs[mt][nt][r] *= inv;
        }
    }
    __syncthreads();
    #pragma unroll
    for (int mt = 0; mt < 2; ++mt)
        #pragma unroll
        for (int nt = 0; nt < 8; ++nt)
            #pragma unroll
            for (int r = 0; r < 4; ++r) {
                int h1 = (wv*2 + mt)*16 + quad*4 + r;
                int h2 = nt*16 + col;
                sh.a[h1][h2] = f2bf(accs[mt][nt][r]);
            }
    __syncthreads();

    const u16* vvs = ws + WS_VT + ((u32)(b*W_ + w))*65536u;   // [cc][h2], 512 rows x 128
    u16* cvout = ws + WS_CV + (u32)(b*C_)*HW_ + (u32)w*H_;    // + cc*HW + h1
    for (int mp = 0; mp < 4; ++mp) {
        f32x4 accv[2][8];
        #pragma unroll
        for (int mi = 0; mi < 2; ++mi)
            #pragma unroll
            for (int nt = 0; nt < 8; ++nt) accv[mi][nt] = (f32x4){0.f,0.f,0.f,0.f};
        #pragma unroll
        for (int ks = 0; ks < 4; ++ks) {
            bf16x8 bfv[8];
            #pragma unroll
            for (int nt = 0; nt < 8; ++nt)
                bfv[nt] = *reinterpret_cast<const bf16x8*>(&sh.a[nt*16 + col][ks*32 + quad*8]);
            #pragma unroll
            for (int mi = 0; mi < 2; ++mi) {
                int ccrow = mp*128 + wv*32 + mi*16 + col;
                bf16x8 af = *reinterpret_cast<const bf16x8*>(&vvs[(u32)ccrow*128u + ks*32 + quad*8]);
                #pragma unroll
                for (int nt = 0; nt < 8; ++nt)
                    accv[mi][nt] = __builtin_amdgcn_mfma_f32_16x16x32_bf16(af, bfv[nt], accv[mi][nt], 0, 0, 0);
            }
        }
        #pragma unroll
        for (int mi = 0; mi < 2; ++mi)
            #pragma unroll
            for (int nt = 0; nt < 8; ++nt)
                #pragma unroll
                for (int r = 0; r < 4; ++r) {
                    int cc = mp*128 + wv*32 + mi*16 + quad*4 + r;
                    int h1 = nt*16 + col;
                    cvout[(u32)cc*HW_ + h1] = f2bf(accv[mi][nt][r]);
                }
    }
}

// ---------------------------------------------------------------------------
// attn_fused: z=0 -> hattn body, z=1 -> vattn body. The two are independent
// (disjoint I/O); fusing doubles blocks-in-flight (each alone is 512 blocks
// = 2/CU, latency-starved) and overlaps hattn's MFMA with vattn's V reads.
// ---------------------------------------------------------------------------
__global__ __launch_bounds__(256) void attn_fused(u16* __restrict__ ws, float* __restrict__ outp)
{
    __shared__ ShF sh;
    if (blockIdx.z == 0) hattn_body(sh, ws, outp);
    else                 vattn_body(sh, ws);
}

// ---------------------------------------------------------------------------
// combine: out = gamma*(ch + cv) + x ; ch f32 in d_out, cv bf16 [b][c][w][h] in ws
// ---------------------------------------------------------------------------
__global__ __launch_bounds__(256) void combine_kernel(const u16* __restrict__ ws, const float* __restrict__ x,
                                                      const float* __restrict__ gamma, float* __restrict__ outp)
{
    __shared__ u16 tl[64][70];   // [h][w]
    const int t = threadIdx.x;
    const int tile = blockIdx.x, cc = blockIdx.y, b = blockIdx.z;
    const int h0 = (tile >> 1) * 64, w0 = (tile & 1) * 64;
    const float g = gamma[0];
    const u32 base = ((u32)(b*C_) + cc) * HW_;
    const u16* cvs = ws + WS_CV + base;   // [w][h]
    #pragma unroll
    for (int pass = 0; pass < 2; ++pass) {
        int ci = pass*256 + t, wl = ci >> 3, h8 = ci & 7;
        uint4 d = *reinterpret_cast<const uint4*>(cvs + (u32)(w0+wl)*H_ + h0 + h8*8);
        const u16* e = reinterpret_cast<const u16*>(&d);
        #pragma unroll
        for (int j = 0; j < 8; ++j) tl[h8*8+j][wl] = e[j];
    }
    __syncthreads();
    #pragma unroll
    for (int pass = 0; pass < 4; ++pass) {
        int ci = pass*256 + t, hl = ci >> 4, w4 = ci & 15;
        u32 idx = base + (u32)(h0+hl)*W_ + w0 + w4*4;
        u32 p0 = *reinterpret_cast<const u32*>(&tl[hl][w4*4]);
        u32 p1 = *reinterpret_cast<const u32*>(&tl[hl][w4*4+2]);
        float4 ch = *reinterpret_cast<const float4*>(outp + idx);
        float4 xx = *reinterpret_cast<const float4*>(x + idx);
        float4 o;
        o.x = g*(ch.x + bf2f((u16)p0))         + xx.x;
        o.y = g*(ch.y + bf2f((u16)(p0 >> 16))) + xx.y;
        o.z = g*(ch.z + bf2f((u16)p1))         + xx.z;
        o.w = g*(ch.w + bf2f((u16)(p1 >> 16))) + xx.w;
        *reinterpret_cast<float4*>(outp + idx) = o;
    }
}

extern "C" void kernel_launch(void* const* d_in, const int* in_sizes, int n_in,
                              void* d_out, int out_size, void* d_ws, size_t ws_size,
                              hipStream_t stream)
{
    const float* x  = (const float*)d_in[0];
    const float* Wq = (const float*)d_in[1];
    const float* bq = (const float*)d_in[2];
    const float* Wk = (const float*)d_in[3];
    const float* bk = (const float*)d_in[4];
    const float* Wv = (const float*)d_in[5];
    const float* bv = (const float*)d_in[6];
    const float* gm = (const float*)d_in[7];
    float* out = (float*)d_out;
    u16* ws  = (u16*)d_ws;

    prep_x<<<dim3(256, 8, 4), 256, 0, stream>>>(x, ws);
    prep_w<<<dim3(320), 256, 0, stream>>>(Wq, Wk, Wv, ws);
    proj_kernel<<<dim3(5, 128, 4), 256, 0, stream>>>(bq, bk, bv, ws);
    transpose_qk<<<dim3(4, 512), 256, 0, stream>>>(ws);
    shuffle_v<<<dim3(4, 128, 4), 256, 0, stream>>>(ws);
    attn_fused<<<dim3(128, 4, 2), 256, 0, stream>>>(ws, out);
    combine_kernel<<<dim3(4, 512, 4), 256, 0, stream>>>(ws, x, gm, out);
}